// Round 9
// baseline (204.241 us; speedup 1.0000x reference)
//
#include <hip/hip_runtime.h>

// ChamferDistance2D: B=8, N=M=8192, fp32, scalar output.
// cost = sum_b [ mean_i min_j d(i,j) + mean_j min_i d(i,j) ],  d = squared L2.
//
// R17: DIAGNOSTIC round (guaranteed-pass). R16 = 3rd blind MFMA correctness
// failure (absmax 6.84 ~ mins over ~16-32 candidates, structural mis-pairing;
// static audit x3 finds nothing). Since top-5 counters only show the SLOWEST
// dispatch, all diagnostics live inside one fused kernel:
//   phase V = R10/R12's proven VALU loop (2048 blocks, IPT=4) -> partial
//             (owns the OUTPUT; round passes regardless of phase M)
//   phase M = R16's MFMA machinery, output-disconnected (kept live via
//             asm-volatile consume, rule #17) + 3 witnesses -> junk writes:
//     I-flag (+0.25KB/blk): A=one-hot identity probe, D must read back B
//                           verbatim => validates A/B/D layout triple.
//     R-flag (+0.5 KB/blk): MFMA row-mins (4 rows) vs exact fp32 recompute.
//     C-flag (+4  KB/blk): MFMA col-mins (4 cols) vs exact fp32 recompute.
// Readout next round: WRITE_SIZE - 8192KB in {0,512,1024,8192,+sums} decodes
// exactly which stage is broken. 0 => MFMA verified, land it pure next.

#define BATCH 8
#define NPTS  8192
#define TPB   256
#define IPT   4
#define PPB   (TPB * IPT)            // 1024
#define TILES (NPTS / PPB)           // 8
#define S     16
#define JCH   (NPTS / S)             // 512
#define PARTN (2 * BATCH * S * NPTS) // 8 MB
#define NPTOT (BATCH * NPTS)         // 65536
#define NTIL  (NPTOT / 16)           // 4096
#define TPB_T (NPTS / 16)            // 512
#define RBLKS (2 * BATCH * NPTS / TPB) // 512
#define GRID2 (BATCH * 16 * 16)      // 2048

typedef __attribute__((ext_vector_type(8))) short short8;
typedef __attribute__((ext_vector_type(4))) float float4v;

__device__ inline float min3f(float a, float b, float c) {
    float d;
    asm("v_min3_f32 %0, %1, %2, %3" : "=v"(d) : "v"(a), "v"(b), "v"(c));
    return d;
}
__device__ inline float2 pkfma(float2 a, float2 b, float2 c) {
    float2 d;
    asm("v_pk_fma_f32 %0, %1, %2, %3" : "=v"(d) : "v"(a), "v"(b), "v"(c));
    return d;
}
__device__ inline ushort bf16rne(float f) {
    uint u = __float_as_uint(f);
    u = u + 0x7FFFu + ((u >> 16) & 1u);
    return (ushort)(u >> 16);
}
__device__ inline float bfloat(ushort h) { return __uint_as_float(((uint)h) << 16); }

// grid.x = 2*NPTOT/TPB = 512: encode points into MFMA frag buffers (R16 form).
__global__ __launch_bounds__(TPB)
void chamfer_prep(const float* __restrict__ p1, const float* __restrict__ p2,
                  ushort* __restrict__ Abuf, ushort* __restrict__ Bbuf) {
    int idx   = blockIdx.x * TPB + threadIdx.x;
    int which = idx >= NPTOT;
    int p     = idx & (NPTOT - 1);
    float2 v = ((const float2*)(which ? p2 : p1))[p];
    float x = v.x, y = v.y;
    float z = fmaf(x, x, y * y);
    ushort xh = bf16rne(x); float xhf = bfloat(xh);
    ushort xl = bf16rne(x - xhf);
    ushort yh = bf16rne(y); float yhf = bfloat(yh);
    ushort yl = bf16rne(y - yhf);
    ushort zh = bf16rne(z); float zhf = bfloat(zh);
    ushort zl = bf16rne(z - zhf);
    const ushort one = 0x3F80;
    int T = p >> 4, row = p & 15;
    short8 zz = {0, 0, 0, 0, 0, 0, 0, 0};
    if (!which) {
        ushort* o = Abuf + (size_t)T * 512 + row * 8;
        short8 k0 = {(short)xh, (short)xh, (short)xl, (short)yh,
                     (short)yh, (short)yl, (short)zh, (short)zl};
        short8 k1 = {(short)one, (short)one, 0, 0, 0, 0, 0, 0};
        *(short8*)(o)       = k0;
        *(short8*)(o + 128) = k1;
        *(short8*)(o + 256) = zz;
        *(short8*)(o + 384) = zz;
    } else {
        ushort m2xh = bf16rne(-2.0f * xhf), m2xl = bf16rne(-2.0f * bfloat(xl));
        ushort m2yh = bf16rne(-2.0f * yhf), m2yl = bf16rne(-2.0f * bfloat(yl));
        ushort* o = Bbuf + (size_t)T * 512 + row * 8;
        short8 k0 = {(short)m2xh, (short)m2xl, (short)m2xh, (short)m2yh,
                     (short)m2yl, (short)m2yh, (short)one, (short)one};
        short8 k1 = {(short)zh, (short)zl, 0, 0, 0, 0, 0, 0};
        *(short8*)(o)       = k0;
        *(short8*)(o + 128) = k1;
        *(short8*)(o + 256) = zz;
        *(short8*)(o + 384) = zz;
    }
}

// grid.x = GRID2 = 2048.  Phase V owns the output; phase M is diagnostics.
__global__ __launch_bounds__(TPB, 4)
void chamfer_partial(const float* __restrict__ p1, const float* __restrict__ p2,
                     const ushort* __restrict__ Abuf, const ushort* __restrict__ Bbuf,
                     float* __restrict__ partial, float* __restrict__ junk) {
    __shared__ __align__(16) float qx[JCH];
    __shared__ __align__(16) float qy[JCH];
    __shared__ __align__(16) float qz[JCH];
    __shared__ float colwave[4][512];
    __shared__ float rwm[4], cwm[4], wredr[4][4], wredc[4][4];
    __shared__ int dflags;

    int bid = blockIdx.x;
    int t   = threadIdx.x;

    // ===== phase V: proven VALU partial (output path), IPT=4 on 2048 blocks
    {
        int split = bid & 15;
        int tile  = (bid >> 4) & 7;
        int b     = (bid >> 7) & 7;
        int dir   = bid >> 10;

        const float2* a  = (const float2*)(dir ? p2 : p1) + (size_t)b * NPTS;
        const float2* bp = (const float2*)(dir ? p1 : p2) + (size_t)b * NPTS + split * JCH;

        for (int j = t; j < JCH; j += TPB) {
            float2 v = bp[j];
            qx[j] = v.x; qy[j] = v.y; qz[j] = fmaf(v.x, v.x, v.y * v.y);
        }

        int pt_base = tile * PPB;
        float2 xp2[IPT], yp2[IPT];
        float  m[IPT];
#pragma unroll
        for (int k = 0; k < IPT; ++k) {
            float2 v = a[pt_base + k * TPB + t];
            xp2[k] = make_float2(-2.0f * v.x, -2.0f * v.x);
            yp2[k] = make_float2(-2.0f * v.y, -2.0f * v.y);
            m[k]   = 3.0e38f;
        }
        __syncthreads();

        for (int j = 0; j < JCH; j += 8) {
            float4 x03 = *(const float4*)&qx[j];
            float4 x47 = *(const float4*)&qx[j + 4];
            float4 y03 = *(const float4*)&qy[j];
            float4 y47 = *(const float4*)&qy[j + 4];
            float4 z03 = *(const float4*)&qz[j];
            float4 z47 = *(const float4*)&qz[j + 4];
            float2 x01 = make_float2(x03.x, x03.y), x23 = make_float2(x03.z, x03.w);
            float2 x45 = make_float2(x47.x, x47.y), x67 = make_float2(x47.z, x47.w);
            float2 y01 = make_float2(y03.x, y03.y), y23 = make_float2(y03.z, y03.w);
            float2 y45 = make_float2(y47.x, y47.y), y67 = make_float2(y47.z, y47.w);
            float2 z01 = make_float2(z03.x, z03.y), z23 = make_float2(z03.z, z03.w);
            float2 z45 = make_float2(z47.x, z47.y), z67 = make_float2(z47.z, z47.w);
#pragma unroll
            for (int k = 0; k < IPT; ++k) {
                float2 a01 = pkfma(yp2[k], y01, pkfma(xp2[k], x01, z01));
                float2 a23 = pkfma(yp2[k], y23, pkfma(xp2[k], x23, z23));
                float2 a45 = pkfma(yp2[k], y45, pkfma(xp2[k], x45, z45));
                float2 a67 = pkfma(yp2[k], y67, pkfma(xp2[k], x67, z67));
                m[k] = min3f(m[k], a01.x, a01.y);
                m[k] = min3f(m[k], a23.x, a23.y);
                m[k] = min3f(m[k], a45.x, a45.y);
                m[k] = min3f(m[k], a67.x, a67.y);
            }
        }

        float* outp = partial + ((size_t)((dir * BATCH + b) * S + split)) * NPTS + pt_base;
#pragma unroll
        for (int k = 0; k < IPT; ++k)
            outp[k * TPB + t] = m[k];
    }

    __syncthreads();
    if (t == 0) dflags = 0;
    __syncthreads();

    // ===== phase M: MFMA diagnostics (no effect on output) ================
    {
        int jblk = bid & 15, iblk = (bid >> 4) & 15, b2 = bid >> 8;
        int w = t >> 6, l = t & 63;
        int lkc = l >> 4, lrow = l & 15;

        short8 afr[8];
        int TA = b2 * TPB_T + iblk * 32 + w * 8;
#pragma unroll
        for (int rt = 0; rt < 8; ++rt)
            afr[rt] = *(const short8*)(Abuf + (size_t)(TA + rt) * 512 + lkc * 128 + lrow * 8);

        float rowmin[8][4];
#pragma unroll
        for (int rt = 0; rt < 8; ++rt)
#pragma unroll
            for (int r = 0; r < 4; ++r) rowmin[rt][r] = 3.0e38f;

        int TB = b2 * TPB_T + jblk * 32;
        const float4v zero = {0.0f, 0.0f, 0.0f, 0.0f};

        for (int ct = 0; ct < 32; ++ct) {
            short8 bf = *(const short8*)(Bbuf + (size_t)(TB + ct) * 512 + lkc * 128 + lrow * 8);
            float colreg = 3.0e38f;
#pragma unroll
            for (int rt = 0; rt < 8; ++rt) {
                float4v c = __builtin_amdgcn_mfma_f32_16x16x32_bf16(afr[rt], bf, zero, 0, 0, 0);
                rowmin[rt][0] = fminf(rowmin[rt][0], c[0]);
                rowmin[rt][1] = fminf(rowmin[rt][1], c[1]);
                rowmin[rt][2] = fminf(rowmin[rt][2], c[2]);
                rowmin[rt][3] = fminf(rowmin[rt][3], c[3]);
                float cc = min3f(c[0], c[1], c[2]);
                colreg = min3f(colreg, cc, c[3]);
            }
            colreg = fminf(colreg, __shfl_xor(colreg, 16, 64));
            colreg = fminf(colreg, __shfl_xor(colreg, 32, 64));
            if (l < 16) colwave[w][ct * 16 + l] = colreg;
        }

        // row-min butterfly over the 16 col-lanes
#pragma unroll
        for (int rt = 0; rt < 8; ++rt)
#pragma unroll
            for (int r = 0; r < 4; ++r) {
                float mm = rowmin[rt][r];
                mm = fminf(mm, __shfl_xor(mm, 1, 64));
                mm = fminf(mm, __shfl_xor(mm, 2, 64));
                mm = fminf(mm, __shfl_xor(mm, 4, 64));
                mm = fminf(mm, __shfl_xor(mm, 8, 64));
                rowmin[rt][r] = mm;
            }
        if (t == 0) {   // wave 0, lkc 0: rowmin[0][r] = block rows 0..3
            rwm[0] = rowmin[0][0]; rwm[1] = rowmin[0][1];
            rwm[2] = rowmin[0][2]; rwm[3] = rowmin[0][3];
        }

        // --- witness I: identity-A probe; D must read back B verbatim ----
        {
            short8 iden = {0, 0, 0, 0, 0, 0, 0, 0};
            int epos = lrow & 7;
            int hit  = (lkc == (lrow >> 3));
#pragma unroll
            for (int e = 0; e < 8; ++e)
                if (e == epos && hit) iden[e] = (short)0x3F80;
            short8 b0 = *(const short8*)(Bbuf + (size_t)TB * 512 + lkc * 128 + lrow * 8);
            float4v dI = __builtin_amdgcn_mfma_f32_16x16x32_bf16(iden, b0, zero, 0, 0, 0);
            bool ibad = false;
#pragma unroll
            for (int r = 0; r < 4; ++r) {
                int k = lkc * 4 + r;   // D row index = B k index under identity-A
                ushort ex = Bbuf[(size_t)TB * 512 + (k >> 3) * 128 + lrow * 8 + (k & 7)];
                float ev = bfloat(ex);
                if (fabsf(dI[r] - ev) > 1e-6f + 1e-3f * fabsf(ev)) ibad = true;
            }
            if (ibad) atomicOr(&dflags, 1);
        }

        __syncthreads();   // colwave complete

        // cross-wave col fold; cw = MFMA col-mins for witness cols 0..3;
        // cs consumes everything (anti-DCE, rule #17)
        float cs = 0.0f;
        for (int c = t; c < 512; c += TPB) {
            float mm = fminf(fminf(colwave[0][c], colwave[1][c]),
                             fminf(colwave[2][c], colwave[3][c]));
            cs += mm;
            if (c < 4) cwm[c] = mm;
        }
#pragma unroll
        for (int rt = 0; rt < 8; ++rt)
#pragma unroll
            for (int r = 0; r < 4; ++r) cs += rowmin[rt][r];
        asm volatile("" :: "v"(cs));

        // --- witnesses R/C: exact fp32 recompute from original points ----
        const float2* P1 = (const float2*)p1 + (size_t)b2 * NPTS;
        const float2* P2 = (const float2*)p2 + (size_t)b2 * NPTS;
        float vr[4], vc[4];
#pragma unroll
        for (int r = 0; r < 4; ++r) { vr[r] = 3.0e38f; vc[r] = 3.0e38f; }
#pragma unroll
        for (int r = 0; r < 4; ++r) {
            float2 A1 = P1[iblk * 512 + r];      // witness row point
            float2 C1 = P2[jblk * 512 + r];      // witness col point
#pragma unroll
            for (int u = 0; u < 2; ++u) {
                int o = t * 2 + u;               // [0,512)
                float2 qb = P2[jblk * 512 + o];
                float dx = A1.x - qb.x, dy = A1.y - qb.y;
                vr[r] = fminf(vr[r], fmaf(dx, dx, dy * dy));
                float2 pa = P1[iblk * 512 + o];
                dx = pa.x - C1.x; dy = pa.y - C1.y;
                vc[r] = fminf(vc[r], fmaf(dx, dx, dy * dy));
            }
        }
#pragma unroll
        for (int r = 0; r < 4; ++r)
#pragma unroll
            for (int off = 32; off > 0; off >>= 1) {
                vr[r] = fminf(vr[r], __shfl_xor(vr[r], off, 64));
                vc[r] = fminf(vc[r], __shfl_xor(vc[r], off, 64));
            }
        if (l == 0) {
#pragma unroll
            for (int r = 0; r < 4; ++r) { wredr[r][w] = vr[r]; wredc[r][w] = vc[r]; }
        }
        __syncthreads();

        if (t == 0) {
            int bad = 0;
#pragma unroll
            for (int r = 0; r < 4; ++r) {
                float er = fminf(fminf(wredr[r][0], wredr[r][1]),
                                 fminf(wredr[r][2], wredr[r][3]));
                float ec = fminf(fminf(wredc[r][0], wredc[r][1]),
                                 fminf(wredc[r][2], wredc[r][3]));
                if (fabsf(er - rwm[r]) > 0.02f) bad |= 2;
                if (fabsf(ec - cwm[r]) > 0.02f) bad |= 4;
            }
            if (bad) atomicOr(&dflags, bad);
        }
        __syncthreads();

        int fl = dflags;
        float* jb = junk + (size_t)bid * 1536;   // 6 KB stride per block
        if ((fl & 1) && t < 64)  jb[t] = cs;                       // I: +0.25 KB
        if ((fl & 2) && t < 128) jb[64 + t] = cs + 1.0f;           // R: +0.5 KB
        if (fl & 4) {                                              // C: +4 KB
#pragma unroll
            for (int e = 0; e < 4; ++e) jb[192 + t * 4 + e] = cs + 2.0f;
        }
    }
}

// grid.x = RBLKS = 512.  Proven R12 reduce (adds |p|^2 back).
__global__ __launch_bounds__(TPB)
void chamfer_reduce(const float* __restrict__ p1, const float* __restrict__ p2,
                    const float* __restrict__ partial, float* __restrict__ bsum) {
    int gid   = blockIdx.x * TPB + threadIdx.x;
    int point = gid & (NPTS - 1);
    int rest  = gid >> 13;
    int b     = rest & (BATCH - 1);
    int dir   = rest >> 3;

    const float* base = partial + ((size_t)(dir * BATCH + b) * S) * NPTS + point;
    float m = base[0];
#pragma unroll
    for (int s = 1; s < S; ++s)
        m = fminf(m, base[(size_t)s * NPTS]);

    float2 v = ((const float2*)(dir ? p2 : p1))[(size_t)b * NPTS + point];
    float d = m + fmaf(v.x, v.x, v.y * v.y);

#pragma unroll
    for (int off = 32; off > 0; off >>= 1)
        d += __shfl_down(d, off, 64);

    __shared__ float wsum[TPB / 64];
    int lane = threadIdx.x & 63;
    int w    = threadIdx.x >> 6;
    if (lane == 0) wsum[w] = d;
    __syncthreads();
    if (threadIdx.x == 0)
        bsum[blockIdx.x] = wsum[0] + wsum[1] + wsum[2] + wsum[3];
}

__global__ __launch_bounds__(TPB)
void chamfer_final(const float* __restrict__ bsum, float* __restrict__ out) {
    int t = threadIdx.x;
    float s = bsum[t] + bsum[t + TPB];
#pragma unroll
    for (int off = 32; off > 0; off >>= 1)
        s += __shfl_down(s, off, 64);
    __shared__ float wsum[TPB / 64];
    int lane = t & 63;
    int w    = t >> 6;
    if (lane == 0) wsum[w] = s;
    __syncthreads();
    if (t == 0)
        *out = (wsum[0] + wsum[1] + wsum[2] + wsum[3]) * (1.0f / NPTS);
}

extern "C" void kernel_launch(void* const* d_in, const int* in_sizes, int n_in,
                              void* d_out, int out_size, void* d_ws, size_t ws_size,
                              hipStream_t stream) {
    const float* p1 = (const float*)d_in[0];
    const float* p2 = (const float*)d_in[1];
    float* out      = (float*)d_out;
    float* partial  = (float*)d_ws;                       // 8 MB
    float* bsum     = partial + PARTN;                    // 4 KB slot
    ushort* Abuf    = (ushort*)(bsum + 1024);             // 4 MB
    ushort* Bbuf    = Abuf + (size_t)NTIL * 512;          // 4 MB
    float* junk     = (float*)(Bbuf + (size_t)NTIL * 512);// 12 MB region

    chamfer_prep<<<2 * NPTOT / TPB, TPB, 0, stream>>>(p1, p2, Abuf, Bbuf);
    chamfer_partial<<<GRID2, TPB, 0, stream>>>(p1, p2, Abuf, Bbuf, partial, junk);
    chamfer_reduce<<<RBLKS, TPB, 0, stream>>>(p1, p2, partial, bsum);
    chamfer_final<<<1, TPB, 0, stream>>>(bsum, out);
}

// Round 10
// 190.904 us; speedup vs baseline: 1.0699x; 1.0699x over previous
//
#include <hip/hip_runtime.h>

// ChamferDistance2D: B=8, N=M=8192, fp32, scalar output.
// cost = sum_b [ mean_i min_j d(i,j) + mean_j min_i d(i,j) ],  d = squared L2.
//
// R19: row-only dual-direction MFMA. R18's witness decode (WRITE_SIZE
// +8192 KB = C-flag exactly, I/R clean): A/B/D fragment layouts and the
// row-min path are HARDWARE-VERIFIED; only the col-min fold is broken
// (bug still invisible to static audit x4). So: use ONLY row-min machinery,
// run both directions as separate block ranges:
//   dir0: A-enc(p1) x B-enc(p2), row-mins -> dist1
//   dir1: A-enc(p2) x B-enc(p1), row-mins -> dist2
// Encoder bytes identical to the verified witnesses. d encoded as K=10 dot
// (bf16 hi/lo): A_i=(xh,xh,xl,yh,yh,yl,zh,zl | 1,1 | 0..),
// B_j=(-2xh',-2xl',-2xh',-2yh',-2yl',-2yh',1,1 | zh',zl' | 0..);
// A.B = |p|^2+|q|^2-2p.q to ~1e-4 << 6.15e-4 threshold. d complete => no
// |p|^2 add in reduce. MFMA doubles vs shared-d (4.19M) but = only ~33us
// pipe time vs the proven 64us VALU wall; 14us of min-VALU overlaps (m114).
// Geometry: 1024 blocks = 2dir x 8b x 16iblk x 4jblk; block = 512 rows x
// 2048 cols; wave w owns rows w*128..+128 (8 A-frags in regs), sweeps 128
// B-tiles. Rowmins butterflied (masks 1,2,4,8 - verified), staged via 2KB
// LDS, coalesced store. partial 2MB (S=4); proven reduce/final backend.

#define BATCH 8
#define NPTS  8192
#define TPB   256
#define S     4
#define PARTN (2 * BATCH * S * NPTS)   // 524288 floats = 2 MB
#define NPTOT (BATCH * NPTS)           // 65536 points per set
#define NTIL  (NPTOT / 16)             // 4096 16-row tiles per set
#define TILB  (NPTS / 16)              // 512 tiles per batch
#define RBLKS (2 * BATCH * NPTS / TPB) // 512
#define GRIDP (2 * BATCH * 16 * S)     // 1024

typedef __attribute__((ext_vector_type(8))) short short8;
typedef __attribute__((ext_vector_type(4))) float float4v;

__device__ inline ushort bf16rne(float f) {
    uint u = __float_as_uint(f);
    u = u + 0x7FFFu + ((u >> 16) & 1u);
    return (ushort)(u >> 16);
}
__device__ inline float bfloat(ushort h) { return __uint_as_float(((uint)h) << 16); }

// Frag layout (hardware-verified by R18's I/R witnesses):
// buffer [tile][kc 0..3][row 0..15][e 0..7] bf16; lane l reads one b128 at
// tile*512 + (l>>4)*128 + (l&15)*8.
// grid.x = 2*NPTOT/TPB = 512: every point -> A-enc AND B-enc of its set.
__global__ __launch_bounds__(TPB)
void chamfer_prep(const float* __restrict__ p1, const float* __restrict__ p2,
                  ushort* __restrict__ A1, ushort* __restrict__ B1,
                  ushort* __restrict__ A2, ushort* __restrict__ B2) {
    int idx   = blockIdx.x * TPB + threadIdx.x;   // [0, 2*NPTOT)
    int which = idx >= NPTOT;                     // 0: p1, 1: p2
    int p     = idx & (NPTOT - 1);
    float2 v = ((const float2*)(which ? p2 : p1))[p];
    float x = v.x, y = v.y;
    float z = fmaf(x, x, y * y);
    ushort xh = bf16rne(x); float xhf = bfloat(xh);
    ushort xl = bf16rne(x - xhf);
    ushort yh = bf16rne(y); float yhf = bfloat(yh);
    ushort yl = bf16rne(y - yhf);
    ushort zh = bf16rne(z); float zhf = bfloat(zh);
    ushort zl = bf16rne(z - zhf);
    const ushort one = 0x3F80;
    int T = p >> 4, row = p & 15;
    short8 zz = {0, 0, 0, 0, 0, 0, 0, 0};

    ushort* Ab = (which ? A2 : A1) + (size_t)T * 512 + row * 8;
    short8 ak0 = {(short)xh, (short)xh, (short)xl, (short)yh,
                  (short)yh, (short)yl, (short)zh, (short)zl};
    short8 ak1 = {(short)one, (short)one, 0, 0, 0, 0, 0, 0};
    *(short8*)(Ab)       = ak0;
    *(short8*)(Ab + 128) = ak1;
    *(short8*)(Ab + 256) = zz;
    *(short8*)(Ab + 384) = zz;

    ushort m2xh = bf16rne(-2.0f * xhf), m2xl = bf16rne(-2.0f * bfloat(xl));
    ushort m2yh = bf16rne(-2.0f * yhf), m2yl = bf16rne(-2.0f * bfloat(yl));
    ushort* Bb = (which ? B2 : B1) + (size_t)T * 512 + row * 8;
    short8 bk0 = {(short)m2xh, (short)m2xl, (short)m2xh, (short)m2yh,
                  (short)m2yl, (short)m2yh, (short)one, (short)one};
    short8 bk1 = {(short)zh, (short)zl, 0, 0, 0, 0, 0, 0};
    *(short8*)(Bb)       = bk0;
    *(short8*)(Bb + 128) = bk1;
    *(short8*)(Bb + 256) = zz;
    *(short8*)(Bb + 384) = zz;
}

// grid.x = GRIDP = 1024.
__global__ __launch_bounds__(TPB, 4)
void chamfer_partial(const ushort* __restrict__ A1, const ushort* __restrict__ B1,
                     const ushort* __restrict__ A2, const ushort* __restrict__ B2,
                     float* __restrict__ partial /* [2][B][S][N] */) {
    __shared__ float rows_lds[512];

    int bid  = blockIdx.x;
    int jblk = bid & (S - 1);
    int iblk = (bid >> 2) & 15;
    int b    = (bid >> 6) & 7;
    int dir  = bid >> 9;

    const ushort* Ab = dir ? A2 : A1;   // rows: p2 for dir1, p1 for dir0
    const ushort* Bb = dir ? B1 : B2;   // cols: the opposite set

    int t = threadIdx.x, w = t >> 6, l = t & 63;
    int lkc = l >> 4, lrow = l & 15;
    size_t fo = (size_t)lkc * 128 + lrow * 8;

    // 8 A-frags = this wave's 128 rows, in registers
    short8 afr[8];
    int TA = b * TILB + iblk * 32 + w * 8;
#pragma unroll
    for (int rt = 0; rt < 8; ++rt)
        afr[rt] = *(const short8*)(Ab + (size_t)(TA + rt) * 512 + fo);

    float rowmin[8][4];
#pragma unroll
    for (int rt = 0; rt < 8; ++rt)
#pragma unroll
        for (int r = 0; r < 4; ++r) rowmin[rt][r] = 3.0e38f;

    int TB = b * TILB + jblk * 128;
    const float4v zero = {0.0f, 0.0f, 0.0f, 0.0f};

    // sweep 128 B-tiles (2048 cols); per ct: 1 b128 + 8 MFMA + 32 fminf.
    for (int ct = 0; ct < 128; ++ct) {
        short8 bf = *(const short8*)(Bb + (size_t)(TB + ct) * 512 + fo);
#pragma unroll
        for (int rt = 0; rt < 8; ++rt) {
            float4v c = __builtin_amdgcn_mfma_f32_16x16x32_bf16(afr[rt], bf, zero, 0, 0, 0);
            rowmin[rt][0] = fminf(rowmin[rt][0], c[0]);
            rowmin[rt][1] = fminf(rowmin[rt][1], c[1]);
            rowmin[rt][2] = fminf(rowmin[rt][2], c[2]);
            rowmin[rt][3] = fminf(rowmin[rt][3], c[3]);
        }
    }

    // row-min butterfly over the 16 col-lanes (verified path: masks 1,2,4,8)
#pragma unroll
    for (int rt = 0; rt < 8; ++rt)
#pragma unroll
        for (int r = 0; r < 4; ++r) {
            float mm = rowmin[rt][r];
            mm = fminf(mm, __shfl_xor(mm, 1, 64));
            mm = fminf(mm, __shfl_xor(mm, 2, 64));
            mm = fminf(mm, __shfl_xor(mm, 4, 64));
            mm = fminf(mm, __shfl_xor(mm, 8, 64));
            rowmin[rt][r] = mm;
        }

    // stage to LDS (rows: w*128 + rt*16 + lkc*4 + r), then coalesced store
    if (lrow == 0) {
#pragma unroll
        for (int rt = 0; rt < 8; ++rt)
#pragma unroll
            for (int r = 0; r < 4; ++r)
                rows_lds[w * 128 + rt * 16 + lkc * 4 + r] = rowmin[rt][r];
    }
    __syncthreads();

    float* op = partial + ((size_t)((dir * BATCH + b) * S + jblk)) * NPTS + iblk * 512;
    op[t]       = rows_lds[t];
    op[t + 256] = rows_lds[t + 256];
}

// grid.x = RBLKS = 512.  partial holds FULL d mins: no |p|^2 add.
__global__ __launch_bounds__(TPB)
void chamfer_reduce(const float* __restrict__ partial, float* __restrict__ bsum) {
    int gid   = blockIdx.x * TPB + threadIdx.x;
    int point = gid & (NPTS - 1);
    int rest  = gid >> 13;
    int b     = rest & (BATCH - 1);
    int dir   = rest >> 3;

    const float* base = partial + ((size_t)(dir * BATCH + b) * S) * NPTS + point;
    float d = base[0];
#pragma unroll
    for (int s = 1; s < S; ++s)
        d = fminf(d, base[(size_t)s * NPTS]);

#pragma unroll
    for (int off = 32; off > 0; off >>= 1)
        d += __shfl_down(d, off, 64);

    __shared__ float wsum[TPB / 64];
    int lane = threadIdx.x & 63;
    int w    = threadIdx.x >> 6;
    if (lane == 0) wsum[w] = d;
    __syncthreads();
    if (threadIdx.x == 0)
        bsum[blockIdx.x] = wsum[0] + wsum[1] + wsum[2] + wsum[3];
}

// grid.x = 1: deterministic final sum.
__global__ __launch_bounds__(TPB)
void chamfer_final(const float* __restrict__ bsum, float* __restrict__ out) {
    int t = threadIdx.x;
    float s = bsum[t] + bsum[t + TPB];
#pragma unroll
    for (int off = 32; off > 0; off >>= 1)
        s += __shfl_down(s, off, 64);
    __shared__ float wsum[TPB / 64];
    int lane = t & 63;
    int w    = t >> 6;
    if (lane == 0) wsum[w] = s;
    __syncthreads();
    if (t == 0)
        *out = (wsum[0] + wsum[1] + wsum[2] + wsum[3]) * (1.0f / NPTS);
}

extern "C" void kernel_launch(void* const* d_in, const int* in_sizes, int n_in,
                              void* d_out, int out_size, void* d_ws, size_t ws_size,
                              hipStream_t stream) {
    const float* p1 = (const float*)d_in[0];
    const float* p2 = (const float*)d_in[1];
    float* out      = (float*)d_out;
    float* partial  = (float*)d_ws;                  // 2 MB
    float* bsum     = partial + PARTN;               // 2 KB (512 floats)
    ushort* A1      = (ushort*)(bsum + 512);         // 4 x 4 MB, 16B-aligned
    ushort* B1      = A1 + (size_t)NTIL * 512;
    ushort* A2      = B1 + (size_t)NTIL * 512;
    ushort* B2      = A2 + (size_t)NTIL * 512;       // total ~18 MB < 32 MB ws

    chamfer_prep<<<2 * NPTOT / TPB, TPB, 0, stream>>>(p1, p2, A1, B1, A2, B2);
    chamfer_partial<<<GRIDP, TPB, 0, stream>>>(A1, B1, A2, B2, partial);
    chamfer_reduce<<<RBLKS, TPB, 0, stream>>>(partial, bsum);
    chamfer_final<<<1, TPB, 0, stream>>>(bsum, out);
}

// Round 11
// 115.909 us; speedup vs baseline: 1.7621x; 1.6470x over previous
//
#include <hip/hip_runtime.h>

// ChamferDistance2D: B=8, N=M=8192, fp32, scalar output.
// cost = sum_b [ mean_i min_j d(i,j) + mean_j min_i d(i,j) ],  d = squared L2.
//
// R20: memory-latency round. R19 PASSED (MFMA d-matrix encoding + row-min
// machinery harness-proven) but partial=138us with MfmaUtil 20% (pipe time
// ~8us), FETCH 24.6MB vs 16MB unique: the B-stream misses L2 (blocks
// sharing a B-slice scattered over XCDs) and the inner loop issues ONE
// dependent load per ct, ~1 deep -> ~900cyc HBM latency exposed per iter.
// Latency wall, not throughput. Fixes:
//  1) XCD swizzle lbid=(bid&7)*128+bid/8 (bijective, 1024=8x128): each XCD
//     owns 2 (dir,b) combos -> 2MB working set < 4MB L2 -> B L2-resident.
//  2) 4-deep register prefetch: unroll ct by 4, load group g+1's tiles
//     ((g+1)&31, never OOB) during group g's 32 MFMA + 128 fminf (~440cyc
//     covers ~200cyc L2). VGPR ~110 < 128 cap at 4 blocks/CU.
// Everything else = R19 verbatim (prep encoder, reduce, final all passed).

#define BATCH 8
#define NPTS  8192
#define TPB   256
#define S     4
#define PARTN (2 * BATCH * S * NPTS)   // 524288 floats = 2 MB
#define NPTOT (BATCH * NPTS)           // 65536 points per set
#define NTIL  (NPTOT / 16)             // 4096 16-row tiles per set
#define TILB  (NPTS / 16)              // 512 tiles per batch
#define RBLKS (2 * BATCH * NPTS / TPB) // 512
#define GRIDP (2 * BATCH * 16 * S)     // 1024

typedef __attribute__((ext_vector_type(8))) short short8;
typedef __attribute__((ext_vector_type(4))) float float4v;

__device__ inline ushort bf16rne(float f) {
    uint u = __float_as_uint(f);
    u = u + 0x7FFFu + ((u >> 16) & 1u);
    return (ushort)(u >> 16);
}
__device__ inline float bfloat(ushort h) { return __uint_as_float(((uint)h) << 16); }

// Frag layout (hardware-verified R18 I/R witnesses, harness-proven R19):
// buffer [tile][kc 0..3][row 0..15][e 0..7] bf16; lane l reads one b128 at
// tile*512 + (l>>4)*128 + (l&15)*8.
__global__ __launch_bounds__(TPB)
void chamfer_prep(const float* __restrict__ p1, const float* __restrict__ p2,
                  ushort* __restrict__ A1, ushort* __restrict__ B1,
                  ushort* __restrict__ A2, ushort* __restrict__ B2) {
    int idx   = blockIdx.x * TPB + threadIdx.x;   // [0, 2*NPTOT)
    int which = idx >= NPTOT;                     // 0: p1, 1: p2
    int p     = idx & (NPTOT - 1);
    float2 v = ((const float2*)(which ? p2 : p1))[p];
    float x = v.x, y = v.y;
    float z = fmaf(x, x, y * y);
    ushort xh = bf16rne(x); float xhf = bfloat(xh);
    ushort xl = bf16rne(x - xhf);
    ushort yh = bf16rne(y); float yhf = bfloat(yh);
    ushort yl = bf16rne(y - yhf);
    ushort zh = bf16rne(z); float zhf = bfloat(zh);
    ushort zl = bf16rne(z - zhf);
    const ushort one = 0x3F80;
    int T = p >> 4, row = p & 15;
    short8 zz = {0, 0, 0, 0, 0, 0, 0, 0};

    ushort* Ab = (which ? A2 : A1) + (size_t)T * 512 + row * 8;
    short8 ak0 = {(short)xh, (short)xh, (short)xl, (short)yh,
                  (short)yh, (short)yl, (short)zh, (short)zl};
    short8 ak1 = {(short)one, (short)one, 0, 0, 0, 0, 0, 0};
    *(short8*)(Ab)       = ak0;
    *(short8*)(Ab + 128) = ak1;
    *(short8*)(Ab + 256) = zz;
    *(short8*)(Ab + 384) = zz;

    ushort m2xh = bf16rne(-2.0f * xhf), m2xl = bf16rne(-2.0f * bfloat(xl));
    ushort m2yh = bf16rne(-2.0f * yhf), m2yl = bf16rne(-2.0f * bfloat(yl));
    ushort* Bb = (which ? B2 : B1) + (size_t)T * 512 + row * 8;
    short8 bk0 = {(short)m2xh, (short)m2xl, (short)m2xh, (short)m2yh,
                  (short)m2yl, (short)m2yh, (short)one, (short)one};
    short8 bk1 = {(short)zh, (short)zl, 0, 0, 0, 0, 0, 0};
    *(short8*)(Bb)       = bk0;
    *(short8*)(Bb + 128) = bk1;
    *(short8*)(Bb + 256) = zz;
    *(short8*)(Bb + 384) = zz;
}

// grid.x = GRIDP = 1024.
__global__ __launch_bounds__(TPB, 4)
void chamfer_partial(const ushort* __restrict__ A1, const ushort* __restrict__ B1,
                     const ushort* __restrict__ A2, const ushort* __restrict__ B2,
                     float* __restrict__ partial /* [2][B][S][N] */) {
    __shared__ float rows_lds[512];

    // XCD-aware swizzle: consecutive physical bids round-robin XCDs; remap so
    // each XCD gets a contiguous logical chunk of 128 (= 2 (dir,b) combos,
    // 2 MB working set, L2-resident). Bijective: 1024 = 8 * 128.
    int bid  = (blockIdx.x & 7) * 128 + (blockIdx.x >> 3);
    int jblk = bid & (S - 1);
    int iblk = (bid >> 2) & 15;
    int b    = (bid >> 6) & 7;
    int dir  = bid >> 9;

    const ushort* Ab = dir ? A2 : A1;   // rows: p2 for dir1, p1 for dir0
    const ushort* Bb = dir ? B1 : B2;   // cols: the opposite set

    int t = threadIdx.x, w = t >> 6, l = t & 63;
    int lkc = l >> 4, lrow = l & 15;
    size_t fo = (size_t)lkc * 128 + lrow * 8;

    // 8 A-frags = this wave's 128 rows, in registers
    short8 afr[8];
    int TA = b * TILB + iblk * 32 + w * 8;
#pragma unroll
    for (int rt = 0; rt < 8; ++rt)
        afr[rt] = *(const short8*)(Ab + (size_t)(TA + rt) * 512 + fo);

    float rowmin[8][4];
#pragma unroll
    for (int rt = 0; rt < 8; ++rt)
#pragma unroll
        for (int r = 0; r < 4; ++r) rowmin[rt][r] = 3.0e38f;

    const ushort* bp = Bb + (size_t)(b * TILB + jblk * 128) * 512 + fo;
    const float4v zero = {0.0f, 0.0f, 0.0f, 0.0f};

    // 4-deep register-prefetch pipeline over 128 B-tiles (32 groups of 4).
    short8 nb0 = *(const short8*)(bp + 0 * 512);
    short8 nb1 = *(const short8*)(bp + 1 * 512);
    short8 nb2 = *(const short8*)(bp + 2 * 512);
    short8 nb3 = *(const short8*)(bp + 3 * 512);
    for (int g = 0; g < 32; ++g) {
        short8 b0 = nb0, b1 = nb1, b2 = nb2, b3 = nb3;
        {   // issue next group's loads before the compute ((g+1)&31: in-bounds)
            const ushort* np = bp + (size_t)(((g + 1) & 31) * 4) * 512;
            nb0 = *(const short8*)(np + 0 * 512);
            nb1 = *(const short8*)(np + 1 * 512);
            nb2 = *(const short8*)(np + 2 * 512);
            nb3 = *(const short8*)(np + 3 * 512);
        }
#pragma unroll
        for (int rt = 0; rt < 8; ++rt) {
            float4v c0 = __builtin_amdgcn_mfma_f32_16x16x32_bf16(afr[rt], b0, zero, 0, 0, 0);
            rowmin[rt][0] = fminf(rowmin[rt][0], c0[0]);
            rowmin[rt][1] = fminf(rowmin[rt][1], c0[1]);
            rowmin[rt][2] = fminf(rowmin[rt][2], c0[2]);
            rowmin[rt][3] = fminf(rowmin[rt][3], c0[3]);
            float4v c1 = __builtin_amdgcn_mfma_f32_16x16x32_bf16(afr[rt], b1, zero, 0, 0, 0);
            rowmin[rt][0] = fminf(rowmin[rt][0], c1[0]);
            rowmin[rt][1] = fminf(rowmin[rt][1], c1[1]);
            rowmin[rt][2] = fminf(rowmin[rt][2], c1[2]);
            rowmin[rt][3] = fminf(rowmin[rt][3], c1[3]);
            float4v c2 = __builtin_amdgcn_mfma_f32_16x16x32_bf16(afr[rt], b2, zero, 0, 0, 0);
            rowmin[rt][0] = fminf(rowmin[rt][0], c2[0]);
            rowmin[rt][1] = fminf(rowmin[rt][1], c2[1]);
            rowmin[rt][2] = fminf(rowmin[rt][2], c2[2]);
            rowmin[rt][3] = fminf(rowmin[rt][3], c2[3]);
            float4v c3 = __builtin_amdgcn_mfma_f32_16x16x32_bf16(afr[rt], b3, zero, 0, 0, 0);
            rowmin[rt][0] = fminf(rowmin[rt][0], c3[0]);
            rowmin[rt][1] = fminf(rowmin[rt][1], c3[1]);
            rowmin[rt][2] = fminf(rowmin[rt][2], c3[2]);
            rowmin[rt][3] = fminf(rowmin[rt][3], c3[3]);
        }
    }

    // row-min butterfly over the 16 col-lanes (verified: masks 1,2,4,8)
#pragma unroll
    for (int rt = 0; rt < 8; ++rt)
#pragma unroll
        for (int r = 0; r < 4; ++r) {
            float mm = rowmin[rt][r];
            mm = fminf(mm, __shfl_xor(mm, 1, 64));
            mm = fminf(mm, __shfl_xor(mm, 2, 64));
            mm = fminf(mm, __shfl_xor(mm, 4, 64));
            mm = fminf(mm, __shfl_xor(mm, 8, 64));
            rowmin[rt][r] = mm;
        }

    // stage to LDS (rows: w*128 + rt*16 + lkc*4 + r), then coalesced store
    if (lrow == 0) {
#pragma unroll
        for (int rt = 0; rt < 8; ++rt)
#pragma unroll
            for (int r = 0; r < 4; ++r)
                rows_lds[w * 128 + rt * 16 + lkc * 4 + r] = rowmin[rt][r];
    }
    __syncthreads();

    float* op = partial + ((size_t)((dir * BATCH + b) * S + jblk)) * NPTS + iblk * 512;
    op[t]       = rows_lds[t];
    op[t + 256] = rows_lds[t + 256];
}

// grid.x = RBLKS = 512.  partial holds FULL d mins: no |p|^2 add.
__global__ __launch_bounds__(TPB)
void chamfer_reduce(const float* __restrict__ partial, float* __restrict__ bsum) {
    int gid   = blockIdx.x * TPB + threadIdx.x;
    int point = gid & (NPTS - 1);
    int rest  = gid >> 13;
    int b     = rest & (BATCH - 1);
    int dir   = rest >> 3;

    const float* base = partial + ((size_t)(dir * BATCH + b) * S) * NPTS + point;
    float d = base[0];
#pragma unroll
    for (int s = 1; s < S; ++s)
        d = fminf(d, base[(size_t)s * NPTS]);

#pragma unroll
    for (int off = 32; off > 0; off >>= 1)
        d += __shfl_down(d, off, 64);

    __shared__ float wsum[TPB / 64];
    int lane = threadIdx.x & 63;
    int w    = threadIdx.x >> 6;
    if (lane == 0) wsum[w] = d;
    __syncthreads();
    if (threadIdx.x == 0)
        bsum[blockIdx.x] = wsum[0] + wsum[1] + wsum[2] + wsum[3];
}

// grid.x = 1: deterministic final sum.
__global__ __launch_bounds__(TPB)
void chamfer_final(const float* __restrict__ bsum, float* __restrict__ out) {
    int t = threadIdx.x;
    float s = bsum[t] + bsum[t + TPB];
#pragma unroll
    for (int off = 32; off > 0; off >>= 1)
        s += __shfl_down(s, off, 64);
    __shared__ float wsum[TPB / 64];
    int lane = t & 63;
    int w    = t >> 6;
    if (lane == 0) wsum[w] = s;
    __syncthreads();
    if (t == 0)
        *out = (wsum[0] + wsum[1] + wsum[2] + wsum[3]) * (1.0f / NPTS);
}

extern "C" void kernel_launch(void* const* d_in, const int* in_sizes, int n_in,
                              void* d_out, int out_size, void* d_ws, size_t ws_size,
                              hipStream_t stream) {
    const float* p1 = (const float*)d_in[0];
    const float* p2 = (const float*)d_in[1];
    float* out      = (float*)d_out;
    float* partial  = (float*)d_ws;                  // 2 MB
    float* bsum     = partial + PARTN;               // 2 KB (512 floats)
    ushort* A1      = (ushort*)(bsum + 512);         // 4 x 4 MB, 16B-aligned
    ushort* B1      = A1 + (size_t)NTIL * 512;
    ushort* A2      = B1 + (size_t)NTIL * 512;
    ushort* B2      = A2 + (size_t)NTIL * 512;       // total ~18 MB < 32 MB ws

    chamfer_prep<<<2 * NPTOT / TPB, TPB, 0, stream>>>(p1, p2, A1, B1, A2, B2);
    chamfer_partial<<<GRIDP, TPB, 0, stream>>>(A1, B1, A2, B2, partial);
    chamfer_reduce<<<RBLKS, TPB, 0, stream>>>(partial, bsum);
    chamfer_final<<<1, TPB, 0, stream>>>(bsum, out);
}